// Round 19
// baseline (99.475 us; speedup 1.0000x reference)
//
#include <hip/hip_runtime.h>

#define NJ 128   // images
#define NI 128   // captions
#define NR 36    // regions
#define NW 32    // words
#define ND 1024  // feature dim

#define LAM_SM 9.0f
#define LAM_LSE 6.0f
#define MARGIN 0.2f
#define EPSF 1e-8f

typedef __attribute__((ext_vector_type(8))) short s16x8;
typedef __attribute__((ext_vector_type(4))) float f32x4;

#define IM_ROWS (NJ * NR)          // 4608
#define S_ROWS  (NI * NW)          // 4096
#define IM_ELEMS (IM_ROWS * ND)
#define S_ELEMS  (S_ROWS * ND)
#define GSW_ELEMS (NJ * 48 * 64)   // bf16, swizzled, zero-padded

// pairG LDS (dynamic, 139264 B): buf = A 288x128B + B 256x128B
#define G_BOFF 36864
#define G_BUFSZ 69632
#define G_SMEM 139264
#define GRAM_SMEM 98304            // gram5: tile 48x2048 [0,98304); overlay partials 8x9984

__device__ __forceinline__ unsigned short f2bf(float x) {
    unsigned u = __float_as_uint(x);
    return (unsigned short)((u + 0x7FFFu + ((u >> 16) & 1u)) >> 16);
}
__device__ __forceinline__ unsigned pack2bf(float x, float y) {
    return (unsigned)f2bf(x) | ((unsigned)f2bf(y) << 16);
}
__device__ __forceinline__ float bf2f(unsigned v) {
    return __uint_as_float((v & 0xffffu) << 16);
}
__device__ __forceinline__ void gload16(const void* g, void* l) {
    __builtin_amdgcn_global_load_lds((const __attribute__((address_space(1))) unsigned int*)g,
                                     (__attribute__((address_space(3))) unsigned int*)l, 16, 0, 0);
}

// ---- s-rows only: f32->bf16 convert + 128B-window swizzle (key=row&7) + fused wnorm ----
__global__ __launch_bounds__(256) void cvts_kernel(const float* __restrict__ s,
                                                   unsigned short* __restrict__ ssw,
                                                   float* __restrict__ w1) {
    __shared__ float part[4];
    const int tid = threadIdx.x;
    int idx = blockIdx.x * 256 + tid;
    int row = idx >> 7, cw = idx & 127;
    int wd = cw >> 3, p = cw & 7;
    int sk = wd * 64 + ((p ^ (row & 7)) * 8);
    const float* srow = s + (size_t)row * ND;
    float4 v0 = *(const float4*)(srow + sk);
    float4 v1 = *(const float4*)(srow + sk + 4);
    ushort4 o0, o1;
    o0.x = f2bf(v0.x); o0.y = f2bf(v0.y); o0.z = f2bf(v0.z); o0.w = f2bf(v0.w);
    o1.x = f2bf(v1.x); o1.y = f2bf(v1.y); o1.z = f2bf(v1.z); o1.w = f2bf(v1.w);
    ((ushort4*)ssw)[(size_t)idx * 2] = o0;
    ((ushort4*)ssw)[(size_t)idx * 2 + 1] = o1;
    float ss = v0.x * v0.x + v0.y * v0.y + v0.z * v0.z + v0.w * v0.w +
               v1.x * v1.x + v1.y * v1.y + v1.z * v1.z + v1.w * v1.w;
    ss += __shfl_xor(ss, 1);  ss += __shfl_xor(ss, 2);  ss += __shfl_xor(ss, 4);
    ss += __shfl_xor(ss, 8);  ss += __shfl_xor(ss, 16); ss += __shfl_xor(ss, 32);
    if ((tid & 63) == 0) part[tid >> 6] = ss;
    __syncthreads();
    if ((tid & 127) == 0)
        w1[row] = sqrtf(part[(tid >> 7) * 2] + part[(tid >> 7) * 2 + 1]);
}

// ---- gram5: fused im-convert + Gram (R17-proven) ----
__global__ __launch_bounds__(512) void gram5_kernel(const float* __restrict__ im,
                                                    unsigned short* __restrict__ imsw,
                                                    unsigned short* __restrict__ Gsw) {
    extern __shared__ char gsm[];
    const int j = blockIdx.x;
    const int tid = threadIdx.x;
    const int wv = tid >> 6, l = tid & 63;
    const int grp = l >> 4, lw = l & 15;
    const int keyadj = (j & 1) * 4;   // (j*36)&7 == 4*(j&1)

#pragma unroll
    for (int u = 0; u < 9; ++u) {
        int e = tid + u * 512;
        int row = e >> 7, cw = e & 127;
        int wd = cw >> 3, p = cw & 7;
        int sk = wd * 64 + ((p ^ ((row + keyadj) & 7)) * 8);
        const float* sp = im + ((size_t)j * 36 + row) * ND + sk;
        float4 v0 = *(const float4*)sp;
        float4 v1 = *(const float4*)(sp + 4);
        int4 pk;
        pk.x = (int)pack2bf(v0.x, v0.y);
        pk.y = (int)pack2bf(v0.z, v0.w);
        pk.z = (int)pack2bf(v1.x, v1.y);
        pk.w = (int)pack2bf(v1.z, v1.w);
        *(int4*)((char*)imsw + ((size_t)j * 36 + row) * 2048 + cw * 16) = pk;
        *(int4*)(gsm + row * 2048 + cw * 16) = pk;
    }
#pragma unroll
    for (int u = 0; u < 3; ++u)
        *(int4*)(gsm + 36 * 2048 + (tid + u * 512) * 16) = make_int4(0, 0, 0, 0);
    __syncthreads();

    f32x4 acc[3][3];
#pragma unroll
    for (int m = 0; m < 3; ++m)
#pragma unroll
        for (int n = 0; n < 3; ++n) acc[m][n] = (f32x4){0.f, 0.f, 0.f, 0.f};

#pragma unroll
    for (int ks = 0; ks < 4; ++ks) {
        const int window = wv * 2 + (ks >> 1);
        s16x8 fr[3];
#pragma unroll
        for (int m = 0; m < 3; ++m) {
            int r = m * 16 + lw;
            int pos = (((ks & 1) * 4 + grp) ^ ((r + keyadj) & 7));
            fr[m] = *(const s16x8*)(gsm + r * 2048 + window * 128 + pos * 16);
        }
#pragma unroll
        for (int m = 0; m < 3; ++m)
#pragma unroll
            for (int n = 0; n < 3; ++n)
                acc[m][n] = __builtin_amdgcn_mfma_f32_16x16x32_bf16(fr[m], fr[n], acc[m][n], 0, 0, 0);
    }
    __syncthreads();
    float* Gt = (float*)(gsm + wv * 9984);
#pragma unroll
    for (int m = 0; m < 3; ++m)
#pragma unroll
        for (int n = 0; n < 3; ++n)
#pragma unroll
            for (int r4 = 0; r4 < 4; ++r4)
                Gt[(m * 16 + grp * 4 + r4) * 52 + n * 16 + lw] = acc[m][n][r4];
    __syncthreads();
    if (tid < 384) {
        int row = tid >> 3, p = tid & 7;
        int k0 = (p ^ (row & 7)) * 8;
        float v[8];
#pragma unroll
        for (int i = 0; i < 8; ++i) {
            int k = k0 + i;
            float sum = 0.f;
            if (k < 48) {
#pragma unroll
                for (int w8 = 0; w8 < 8; ++w8)
                    sum += ((const float*)(gsm + w8 * 9984))[row * 52 + k];
            }
            v[i] = sum;
        }
        ushort4 o0, o1;
        o0.x = f2bf(v[0]); o0.y = f2bf(v[1]); o0.z = f2bf(v[2]); o0.w = f2bf(v[3]);
        o1.x = f2bf(v[4]); o1.y = f2bf(v[5]); o1.z = f2bf(v[6]); o1.w = f2bf(v[7]);
        ushort4* dp = (ushort4*)((char*)Gsw + (size_t)j * 6144 + row * 128 + p * 16);
        dp[0] = o0; dp[1] = o1;
    }
}

// ---- pairG: PURE GEMM with COUNTED-vmcnt pipeline (T4 on the acc[9][4] kernel) ----
// R15/R18 loop drained the prefetch (vmcnt(0) after stage(t+1)); here each iter
// waits only for the tile about to be computed: waves 0-3 issue 9 loads/tile
// (5 A + 4 B), waves 4-7 issue 8 (4 A + 4 B) -> vmcnt(9)/vmcnt(8). Second barrier
// per iter protects buf[t&1] before stage(t+2) overwrites it.
__global__ __attribute__((amdgpu_flat_work_group_size(512, 512)))
__attribute__((amdgpu_waves_per_eu(2, 2)))
void pairG_kernel(const unsigned short* __restrict__ imsw,
                  const unsigned short* __restrict__ ssw,
                  unsigned* __restrict__ C) {
    extern __shared__ char smem[];
    const int ig = blockIdx.x;   // caption octet
    const int jg = blockIdx.y;   // image octet
    const int tid = threadIdx.x;
    const int l = tid & 63, wv = tid >> 6;
    const int grp = l >> 4, lw = l & 15;
    const int wm = wv >> 2, wn = wv & 3;

    const char* aSrc = (const char*)imsw + ((size_t)(jg * 288) + (l >> 3)) * 2048 + (l & 7) * 16;
    const char* bSrc = (const char*)ssw + ((size_t)(ig * 256) + (l >> 3)) * 2048 + (l & 7) * 16;

    f32x4 acc[9][4];
#pragma unroll
    for (int m = 0; m < 9; ++m)
#pragma unroll
        for (int n = 0; n < 4; ++n) acc[m][n] = (f32x4){0.f, 0.f, 0.f, 0.f};

    auto stage = [&](int bb, int k0b) {
        char* ab = smem + bb;
#pragma unroll
        for (int t = 0; t < 5; ++t) {
            int ii = wv + 8 * t;
            if (ii < 36) gload16(aSrc + (size_t)ii * 16384 + k0b, ab + ii * 1024);
        }
        char* bbp = smem + bb + G_BOFF;
#pragma unroll
        for (int t = 0; t < 4; ++t) {
            int ii = wv + 8 * t;
            gload16(bSrc + (size_t)ii * 16384 + k0b, bbp + ii * 1024);
        }
    };
    auto compute = [&](int bb) {
        const char* A = smem + bb;
        const char* B = smem + bb + G_BOFF;
#pragma unroll
        for (int ks = 0; ks < 2; ++ks) {
            const int swz = (((ks * 4 + grp) ^ (lw & 7)) << 4);
            s16x8 bf[4];
#pragma unroll
            for (int n = 0; n < 4; ++n)
                bf[n] = *(const s16x8*)(B + (wn * 64 + n * 16 + lw) * 128 + swz);
#pragma unroll
            for (int m = 0; m < 9; ++m) {
                s16x8 a = *(const s16x8*)(A + (wm * 144 + m * 16 + lw) * 128 + swz);
#pragma unroll
                for (int n = 0; n < 4; ++n)
                    acc[m][n] = __builtin_amdgcn_mfma_f32_16x16x32_bf16(a, bf[n], acc[m][n], 0, 0, 0);
            }
        }
    };

    stage(0, 0);
    stage(G_BUFSZ, 128);
    for (int t = 0; t < 16; ++t) {
        // wait ONLY for tile t; tile t+1 stays in flight
        if (t < 15) {
            if (wv < 4) asm volatile("s_waitcnt vmcnt(9)" ::: "memory");
            else        asm volatile("s_waitcnt vmcnt(8)" ::: "memory");
        } else {
            asm volatile("s_waitcnt vmcnt(0)" ::: "memory");
        }
        __builtin_amdgcn_s_barrier();
        __builtin_amdgcn_sched_barrier(0);
        compute((t & 1) * G_BUFSZ);
        asm volatile("s_waitcnt lgkmcnt(0)" ::: "memory");
        __builtin_amdgcn_sched_barrier(0);
        __builtin_amdgcn_s_barrier();
        if (t < 14) stage((t & 1) * G_BUFSZ, (t + 2) * 128);
    }

    // C-store: bf16 pairs; ONLY rows belonging to image L (pad rows never read)
#pragma unroll
    for (int L = 0; L < 4; ++L)
#pragma unroll
        for (int mm3 = 0; mm3 < 3; ++mm3) {
            const int m = 2 * L + mm3;
            const int rbase = m * 16 + grp * 4;
            const bool pred = ((rbase * 1821) >> 16) == L;
#pragma unroll
            for (int n = 0; n < 4; ++n) {
                const int p = (jg * 8 + wm * 4 + L) * NI + ig * 8 + wn * 2 + (n >> 1);
                const int nn = n & 1;
                size_t idx = ((size_t)(p * 3 + mm3) * 2 + nn) * 128 + l * 2;
                if (pred) {
                    uint2 v;
                    v.x = pack2bf(acc[m][n][0], acc[m][n][1]);
                    v.y = pack2bf(acc[m][n][2], acc[m][n][3]);
                    *(uint2*)(C + idx) = v;
                }
            }
        }
}

// ---- pairE: epilogue, 1 wave = 1 pair; 256-thr blocks (R18-proven) ----
__global__ __launch_bounds__(256) void pairE_kernel(const unsigned* __restrict__ C,
                                                    const unsigned short* __restrict__ Gswp,
                                                    const float* __restrict__ w1g,
                                                    float* __restrict__ scores) {
    __shared__ __align__(16) char smem[22528];
    const int ib = blockIdx.x;   // caption quad
    const int j = blockIdx.y;    // image
    const int tid = threadIdx.x;
    const int l = tid & 63, wv = tid >> 6;
    const int grp = l >> 4, lw = l & 15;
    const int i = ib * 4 + wv;
    const int p = j * NI + i;
    const int L = j & 3;
    char* const Gd = smem;
    char* const myE = smem + 6144 + wv * 4096;

    for (int u = tid; u < 384; u += 256)
        *(int4*)(Gd + u * 16) = *(const int4*)((const char*)Gswp + (size_t)j * 6144 + u * 16);

    uint2 cv[3][2];
#pragma unroll
    for (int mm3 = 0; mm3 < 3; ++mm3) {
        const int rbase = (2 * L + mm3) * 16 + grp * 4;
        const bool pred = ((rbase * 1821) >> 16) == L;
#pragma unroll
        for (int nn = 0; nn < 2; ++nn)
            cv[mm3][nn] = pred
                ? *(const uint2*)(C + ((size_t)(p * 3 + mm3) * 2 + nn) * 128 + l * 2)
                : make_uint2(0u, 0u);
    }

#pragma unroll
    for (int u = 0; u < 7; ++u) {
        int e = l + u * 64;
        int w = e / 14, pr = e - w * 14 + 18;
        *(unsigned*)(myE + w * 128 + (((pr >> 2) ^ (w & 7)) << 4) + (pr & 3) * 4) = 0u;
    }

#define AV(mm3, nn, reg) ((reg) == 0 ? bf2f(cv[mm3][nn].x) : (reg) == 1 ? bf2f(cv[mm3][nn].x >> 16) \
                          : (reg) == 2 ? bf2f(cv[mm3][nn].y) : bf2f(cv[mm3][nn].y >> 16))

    float inv[3][4];
#pragma unroll
    for (int mm3 = 0; mm3 < 3; ++mm3)
#pragma unroll
        for (int reg = 0; reg < 4; ++reg) {
            float a0 = AV(mm3, 0, reg), a1 = AV(mm3, 1, reg);
            float l0 = a0 > 0.f ? a0 : 0.1f * a0;
            float l1 = a1 > 0.f ? a1 : 0.1f * a1;
            float ss = l0 * l0 + l1 * l1;
            ss += __shfl_xor(ss, 1); ss += __shfl_xor(ss, 2);
            ss += __shfl_xor(ss, 4); ss += __shfl_xor(ss, 8);
            inv[mm3][reg] = 1.f / (sqrtf(ss) + EPSF);
        }

    float mx[2] = {-1e30f, -1e30f};
#pragma unroll
    for (int mm3 = 0; mm3 < 3; ++mm3) {
        int rbase = (2 * L + mm3) * 16 + grp * 4;
        bool pred = ((rbase * 1821) >> 16) == L;
#pragma unroll
        for (int nn = 0; nn < 2; ++nn) {
            float t4 = -1e30f;
#pragma unroll
            for (int reg = 0; reg < 4; ++reg) {
                float a = AV(mm3, nn, reg);
                float lk = a > 0.f ? a : 0.1f * a;
                t4 = fmaxf(t4, LAM_SM * lk * inv[mm3][reg]);
            }
            mx[nn] = pred ? fmaxf(mx[nn], t4) : mx[nn];
        }
    }
#pragma unroll
    for (int nn = 0; nn < 2; ++nn) {
        mx[nn] = fmaxf(mx[nn], __shfl_xor(mx[nn], 16));
        mx[nn] = fmaxf(mx[nn], __shfl_xor(mx[nn], 32));
    }

    float dn[2] = {0.f, 0.f}, nm[2] = {0.f, 0.f};
#pragma unroll
    for (int mm3 = 0; mm3 < 3; ++mm3) {
        int rbase = (2 * L + mm3) * 16 + grp * 4;
        bool pred = ((rbase * 1821) >> 16) == L;
        int rl0 = rbase - 36 * L;
#pragma unroll
        for (int nn = 0; nn < 2; ++nn) {
            int w = nn * 16 + lw;
            float e[4];
#pragma unroll
            for (int reg = 0; reg < 4; ++reg) {
                float a = AV(mm3, nn, reg);
                float lk = a > 0.f ? a : 0.1f * a;
                float tl = LAM_SM * lk * inv[mm3][reg];
                e[reg] = pred ? __expf(tl - mx[nn]) : 0.f;
                dn[nn] += e[reg];
                nm[nn] += e[reg] * a;
            }
            if (pred) {
                char* base = myE + w * 128 + (((rl0 >> 3) ^ (w & 7)) << 4) + (rl0 & 7) * 2;
                *(unsigned*)(base) = pack2bf(e[0], e[1]);
                *(unsigned*)(base + 4) = pack2bf(e[2], e[3]);
            }
        }
    }
#pragma unroll
    for (int nn = 0; nn < 2; ++nn) {
        dn[nn] += __shfl_xor(dn[nn], 16); dn[nn] += __shfl_xor(dn[nn], 32);
        nm[nn] += __shfl_xor(nm[nn], 16); nm[nn] += __shfl_xor(nm[nn], 32);
    }
    __syncthreads();

    f32x4 u[3][2];
#pragma unroll
    for (int m = 0; m < 3; ++m)
#pragma unroll
        for (int nn = 0; nn < 2; ++nn) u[m][nn] = (f32x4){0.f, 0.f, 0.f, 0.f};
#pragma unroll
    for (int ks = 0; ks < 2; ++ks) {
        int sz2 = (((ks * 4 + grp) ^ (lw & 7)) << 4);
        s16x8 ga[3], eb[2];
#pragma unroll
        for (int m = 0; m < 3; ++m)
            ga[m] = *(const s16x8*)(Gd + (m * 16 + lw) * 128 + sz2);
#pragma unroll
        for (int nn = 0; nn < 2; ++nn) {
            int w = nn * 16 + lw;
            eb[nn] = *(const s16x8*)(myE + w * 128 + (((ks * 4 + grp) ^ (w & 7)) << 4));
        }
#pragma unroll
        for (int m = 0; m < 3; ++m)
#pragma unroll
            for (int nn = 0; nn < 2; ++nn)
                u[m][nn] = __builtin_amdgcn_mfma_f32_16x16x32_bf16(ga[m], eb[nn], u[m][nn], 0, 0, 0);
    }
    float qq[2] = {0.f, 0.f};
#pragma unroll
    for (int m = 0; m < 3; ++m)
#pragma unroll
        for (int nn = 0; nn < 2; ++nn) {
            int w = nn * 16 + lw;
            const char* base = myE + w * 128;
#pragma unroll
            for (int rg = 0; rg < 4; rg += 2) {
                int rp = m * 16 + grp * 4 + rg;
                unsigned pv = *(const unsigned*)(base + (((rp >> 3) ^ (w & 7)) << 4) + (rp & 7) * 2);
                qq[nn] += u[m][nn][rg] * bf2f(pv) + u[m][nn][rg + 1] * bf2f(pv >> 16);
            }
        }
#pragma unroll
    for (int nn = 0; nn < 2; ++nn) {
        qq[nn] += __shfl_xor(qq[nn], 16); qq[nn] += __shfl_xor(qq[nn], 32);
    }
    float w1a = w1g[i * 32 + lw], w1b = w1g[i * 32 + 16 + lw];
    float s0 = nm[0] / fmaxf(w1a * sqrtf(fmaxf(qq[0], 0.f)), EPSF * dn[0]);
    float s1 = nm[1] / fmaxf(w1b * sqrtf(fmaxf(qq[1], 0.f)), EPSF * dn[1]);
    float m2 = fmaxf(s0, s1);
    m2 = fmaxf(m2, __shfl_xor(m2, 1)); m2 = fmaxf(m2, __shfl_xor(m2, 2));
    m2 = fmaxf(m2, __shfl_xor(m2, 4)); m2 = fmaxf(m2, __shfl_xor(m2, 8));
    float ssum = __expf(LAM_LSE * (s0 - m2)) + __expf(LAM_LSE * (s1 - m2));
    ssum += __shfl_xor(ssum, 1); ssum += __shfl_xor(ssum, 2);
    ssum += __shfl_xor(ssum, 4); ssum += __shfl_xor(ssum, 8);
    if (l == 0) scores[p] = m2 + logf(ssum) / LAM_LSE;
#undef AV
}

// ---- final hinge loss: 1024 threads, 4-way split per row/col (R15-proven) ----
__global__ __launch_bounds__(1024) void loss_kernel(const float* __restrict__ scores,
                                                    float* __restrict__ out) {
    __shared__ float diag[NJ];
    __shared__ float part[1024];
    __shared__ float red[256];
    const int tid = threadIdx.x;
    if (tid < NJ) diag[tid] = scores[tid * NI + tid];
    __syncthreads();
    const int unit = tid >> 2, q = tid & 3;
    float m = 0.f;
    if (unit < 128) {
        const int a = unit;
        const float da = diag[a];
        for (int k = 0; k < 32; ++k) {
            int b = q * 32 + k;
            float c = MARGIN + scores[a * NI + b] - da;
            if (b != a) m = fmaxf(m, c);
        }
    } else {
        const int b = unit - 128;
        const float db = diag[b];
        for (int k = 0; k < 32; ++k) {
            int a = q * 32 + k;
            float c = MARGIN + scores[a * NI + b] - db;
            if (a != b) m = fmaxf(m, c);
        }
    }
    part[tid] = m;
    __syncthreads();
    if (q == 0)
        red[unit] = fmaxf(fmaxf(part[tid], part[tid + 1]), fmaxf(part[tid + 2], part[tid + 3]));
    __syncthreads();
    for (int st = 128; st > 0; st >>= 1) {
        if (tid < st) red[tid] += red[tid + st];
        __syncthreads();
    }
    if (tid == 0) out[0] = red[0];
}

extern "C" void kernel_launch(void* const* d_in, const int* in_sizes, int n_in,
                              void* d_out, int out_size, void* d_ws, size_t ws_size,
                              hipStream_t stream) {
    const float* im = (const float*)d_in[0];
    const float* s = (const float*)d_in[1];

    unsigned short* imsw = (unsigned short*)d_ws;
    unsigned short* ssw = imsw + IM_ELEMS;
    unsigned short* Gswp = ssw + S_ELEMS;
    float* w1 = (float*)(Gswp + GSW_ELEMS);
    float* scores = w1 + S_ROWS;
    unsigned* C = (unsigned*)(scores + NJ * NI);

    hipFuncSetAttribute((const void*)pairG_kernel,
                        hipFuncAttributeMaxDynamicSharedMemorySize, G_SMEM);
    hipFuncSetAttribute((const void*)gram5_kernel,
                        hipFuncAttributeMaxDynamicSharedMemorySize, GRAM_SMEM);

    cvts_kernel<<<dim3(S_ROWS / 2), dim3(256), 0, stream>>>(s, ssw, w1);
    gram5_kernel<<<dim3(NJ), dim3(512), GRAM_SMEM, stream>>>(im, imsw, Gswp);
    pairG_kernel<<<dim3(NI / 8, NJ / 8), dim3(512), G_SMEM, stream>>>(imsw, ssw, C);
    pairE_kernel<<<dim3(NI / 4, NJ), dim3(256), 0, stream>>>(C, Gswp, w1, scores);
    loss_kernel<<<dim3(1), dim3(1024), 0, stream>>>(scores, (float*)d_out);
}

// Round 20
// 93.858 us; speedup vs baseline: 1.0598x; 1.0598x over previous
//
#include <hip/hip_runtime.h>

#define NJ 128   // images
#define NI 128   // captions
#define NR 36    // regions
#define NW 32    // words
#define ND 1024  // feature dim

#define LAM_SM 9.0f
#define LAM_LSE 6.0f
#define MARGIN 0.2f
#define EPSF 1e-8f

typedef __attribute__((ext_vector_type(8))) short s16x8;
typedef __attribute__((ext_vector_type(4))) float f32x4;

#define IM_ROWS (NJ * NR)          // 4608
#define S_ROWS  (NI * NW)          // 4096
#define IM_ELEMS (IM_ROWS * ND)
#define S_ELEMS  (S_ROWS * ND)
#define GSW_ELEMS (NJ * 48 * 64)   // bf16, swizzled, zero-padded

// pairG LDS (dynamic, 139264 B): buf = A 288x128B + B 256x128B
#define G_BOFF 36864
#define G_BUFSZ 69632
#define G_SMEM 139264
#define GRAM_SMEM 98304            // prep: gram tile 48x2048 [0,98304); overlay partials 8x9984

__device__ __forceinline__ unsigned short f2bf(float x) {
    unsigned u = __float_as_uint(x);
    return (unsigned short)((u + 0x7FFFu + ((u >> 16) & 1u)) >> 16);
}
__device__ __forceinline__ unsigned pack2bf(float x, float y) {
    return (unsigned)f2bf(x) | ((unsigned)f2bf(y) << 16);
}
__device__ __forceinline__ float bf2f(unsigned v) {
    return __uint_as_float((v & 0xffffu) << 16);
}
__device__ __forceinline__ void gload16(const void* g, void* l) {
    __builtin_amdgcn_global_load_lds((const __attribute__((address_space(1))) unsigned int*)g,
                                     (__attribute__((address_space(3))) unsigned int*)l, 16, 0, 0);
}

// ---- prep: blocks [0,NJ) = fused im-convert + Gram (gram5 body);
//            blocks [NJ, NJ+1024) = s-convert (4 rows/block) + fused wnorm ----
__global__ __launch_bounds__(512) void prep_kernel(const float* __restrict__ im,
                                                   const float* __restrict__ s,
                                                   unsigned short* __restrict__ imsw,
                                                   unsigned short* __restrict__ ssw,
                                                   float* __restrict__ w1,
                                                   unsigned short* __restrict__ Gsw) {
    extern __shared__ char gsm[];
    const int tid = threadIdx.x;

    if (blockIdx.x >= NJ) {
        // ---------- s-convert branch ----------
        float* part = (float*)gsm;   // 8 floats
        int idx = (blockIdx.x - NJ) * 512 + tid;   // task over S_ROWS*128
        int row = idx >> 7, cw = idx & 127;
        int wd = cw >> 3, p = cw & 7;
        int sk = wd * 64 + ((p ^ (row & 7)) * 8);
        const float* srow = s + (size_t)row * ND;
        float4 v0 = *(const float4*)(srow + sk);
        float4 v1 = *(const float4*)(srow + sk + 4);
        ushort4 o0, o1;
        o0.x = f2bf(v0.x); o0.y = f2bf(v0.y); o0.z = f2bf(v0.z); o0.w = f2bf(v0.w);
        o1.x = f2bf(v1.x); o1.y = f2bf(v1.y); o1.z = f2bf(v1.z); o1.w = f2bf(v1.w);
        ((ushort4*)ssw)[(size_t)idx * 2] = o0;
        ((ushort4*)ssw)[(size_t)idx * 2 + 1] = o1;
        float ss = v0.x * v0.x + v0.y * v0.y + v0.z * v0.z + v0.w * v0.w +
                   v1.x * v1.x + v1.y * v1.y + v1.z * v1.z + v1.w * v1.w;
        ss += __shfl_xor(ss, 1);  ss += __shfl_xor(ss, 2);  ss += __shfl_xor(ss, 4);
        ss += __shfl_xor(ss, 8);  ss += __shfl_xor(ss, 16); ss += __shfl_xor(ss, 32);
        if ((tid & 63) == 0) part[tid >> 6] = ss;
        __syncthreads();
        if ((tid & 127) == 0)
            w1[row] = sqrtf(part[(tid >> 7) * 2] + part[(tid >> 7) * 2 + 1]);
        return;
    }

    // ---------- gram branch (R17-proven gram5 body) ----------
    const int j = blockIdx.x;
    const int wv = tid >> 6, l = tid & 63;
    const int grp = l >> 4, lw = l & 15;
    const int keyadj = (j & 1) * 4;   // (j*36)&7 == 4*(j&1)

#pragma unroll
    for (int u = 0; u < 9; ++u) {
        int e = tid + u * 512;
        int row = e >> 7, cw = e & 127;
        int wd = cw >> 3, p = cw & 7;
        int sk = wd * 64 + ((p ^ ((row + keyadj) & 7)) * 8);
        const float* sp = im + ((size_t)j * 36 + row) * ND + sk;
        float4 v0 = *(const float4*)sp;
        float4 v1 = *(const float4*)(sp + 4);
        int4 pk;
        pk.x = (int)pack2bf(v0.x, v0.y);
        pk.y = (int)pack2bf(v0.z, v0.w);
        pk.z = (int)pack2bf(v1.x, v1.y);
        pk.w = (int)pack2bf(v1.z, v1.w);
        *(int4*)((char*)imsw + ((size_t)j * 36 + row) * 2048 + cw * 16) = pk;
        *(int4*)(gsm + row * 2048 + cw * 16) = pk;
    }
#pragma unroll
    for (int u = 0; u < 3; ++u)
        *(int4*)(gsm + 36 * 2048 + (tid + u * 512) * 16) = make_int4(0, 0, 0, 0);
    __syncthreads();

    f32x4 acc[3][3];
#pragma unroll
    for (int m = 0; m < 3; ++m)
#pragma unroll
        for (int n = 0; n < 3; ++n) acc[m][n] = (f32x4){0.f, 0.f, 0.f, 0.f};

#pragma unroll
    for (int ks = 0; ks < 4; ++ks) {
        const int window = wv * 2 + (ks >> 1);
        s16x8 fr[3];
#pragma unroll
        for (int m = 0; m < 3; ++m) {
            int r = m * 16 + lw;
            int pos = (((ks & 1) * 4 + grp) ^ ((r + keyadj) & 7));
            fr[m] = *(const s16x8*)(gsm + r * 2048 + window * 128 + pos * 16);
        }
#pragma unroll
        for (int m = 0; m < 3; ++m)
#pragma unroll
            for (int n = 0; n < 3; ++n)
                acc[m][n] = __builtin_amdgcn_mfma_f32_16x16x32_bf16(fr[m], fr[n], acc[m][n], 0, 0, 0);
    }
    __syncthreads();
    float* Gt = (float*)(gsm + wv * 9984);
#pragma unroll
    for (int m = 0; m < 3; ++m)
#pragma unroll
        for (int n = 0; n < 3; ++n)
#pragma unroll
            for (int r4 = 0; r4 < 4; ++r4)
                Gt[(m * 16 + grp * 4 + r4) * 52 + n * 16 + lw] = acc[m][n][r4];
    __syncthreads();
    if (tid < 384) {
        int row = tid >> 3, p = tid & 7;
        int k0 = (p ^ (row & 7)) * 8;
        float v[8];
#pragma unroll
        for (int i = 0; i < 8; ++i) {
            int k = k0 + i;
            float sum = 0.f;
            if (k < 48) {
#pragma unroll
                for (int w8 = 0; w8 < 8; ++w8)
                    sum += ((const float*)(gsm + w8 * 9984))[row * 52 + k];
            }
            v[i] = sum;
        }
        ushort4 o0, o1;
        o0.x = f2bf(v[0]); o0.y = f2bf(v[1]); o0.z = f2bf(v[2]); o0.w = f2bf(v[3]);
        o1.x = f2bf(v[4]); o1.y = f2bf(v[5]); o1.z = f2bf(v[6]); o1.w = f2bf(v[7]);
        ushort4* dp = (ushort4*)((char*)Gsw + (size_t)j * 6144 + row * 128 + p * 16);
        dp[0] = o0; dp[1] = o1;
    }
}

// ---- pairG: PURE GEMM (R18-proven ~40us): dbuf K_STEP=64, drain-style loop,
// acc[9][4]=144 AGPR, predicated C-store (pad rows skipped). Counted-vmcnt (R13,
// R19) and K_STEP=128 (R16) both regressed — this is the 2-barrier optimum. ----
__global__ __attribute__((amdgpu_flat_work_group_size(512, 512)))
__attribute__((amdgpu_waves_per_eu(2, 2)))
void pairG_kernel(const unsigned short* __restrict__ imsw,
                  const unsigned short* __restrict__ ssw,
                  unsigned* __restrict__ C) {
    extern __shared__ char smem[];
    const int ig = blockIdx.x;   // caption octet
    const int jg = blockIdx.y;   // image octet
    const int tid = threadIdx.x;
    const int l = tid & 63, wv = tid >> 6;
    const int grp = l >> 4, lw = l & 15;
    const int wm = wv >> 2, wn = wv & 3;

    const char* aSrc = (const char*)imsw + ((size_t)(jg * 288) + (l >> 3)) * 2048 + (l & 7) * 16;
    const char* bSrc = (const char*)ssw + ((size_t)(ig * 256) + (l >> 3)) * 2048 + (l & 7) * 16;

    f32x4 acc[9][4];
#pragma unroll
    for (int m = 0; m < 9; ++m)
#pragma unroll
        for (int n = 0; n < 4; ++n) acc[m][n] = (f32x4){0.f, 0.f, 0.f, 0.f};

    auto stage = [&](int bb, int k0b) {
        char* ab = smem + bb;
#pragma unroll
        for (int t = 0; t < 5; ++t) {
            int ii = wv + 8 * t;
            if (ii < 36) gload16(aSrc + (size_t)ii * 16384 + k0b, ab + ii * 1024);
        }
        char* bbp = smem + bb + G_BOFF;
#pragma unroll
        for (int t = 0; t < 4; ++t) {
            int ii = wv + 8 * t;
            gload16(bSrc + (size_t)ii * 16384 + k0b, bbp + ii * 1024);
        }
    };
    auto compute = [&](int bb) {
        const char* A = smem + bb;
        const char* B = smem + bb + G_BOFF;
#pragma unroll
        for (int ks = 0; ks < 2; ++ks) {
            const int swz = (((ks * 4 + grp) ^ (lw & 7)) << 4);
            s16x8 bf[4];
#pragma unroll
            for (int n = 0; n < 4; ++n)
                bf[n] = *(const s16x8*)(B + (wn * 64 + n * 16 + lw) * 128 + swz);
#pragma unroll
            for (int m = 0; m < 9; ++m) {
                s16x8 a = *(const s16x8*)(A + (wm * 144 + m * 16 + lw) * 128 + swz);
#pragma unroll
                for (int n = 0; n < 4; ++n)
                    acc[m][n] = __builtin_amdgcn_mfma_f32_16x16x32_bf16(a, bf[n], acc[m][n], 0, 0, 0);
            }
        }
    };

    stage(0, 0);
    asm volatile("s_waitcnt vmcnt(0)" ::: "memory");
    __syncthreads();
    for (int t = 0; t < 16; ++t) {
        if (t < 15) stage(((t + 1) & 1) * G_BUFSZ, (t + 1) * 128);
        compute((t & 1) * G_BUFSZ);
        asm volatile("s_waitcnt vmcnt(0)" ::: "memory");
        __syncthreads();
    }

    // C-store: bf16 pairs; ONLY rows belonging to image L (pad rows never read)
#pragma unroll
    for (int L = 0; L < 4; ++L)
#pragma unroll
        for (int mm3 = 0; mm3 < 3; ++mm3) {
            const int m = 2 * L + mm3;
            const int rbase = m * 16 + grp * 4;
            const bool pred = ((rbase * 1821) >> 16) == L;
#pragma unroll
            for (int n = 0; n < 4; ++n) {
                const int p = (jg * 8 + wm * 4 + L) * NI + ig * 8 + wn * 2 + (n >> 1);
                const int nn = n & 1;
                size_t idx = ((size_t)(p * 3 + mm3) * 2 + nn) * 128 + l * 2;
                if (pred) {
                    uint2 v;
                    v.x = pack2bf(acc[m][n][0], acc[m][n][1]);
                    v.y = pack2bf(acc[m][n][2], acc[m][n][3]);
                    *(uint2*)(C + idx) = v;
                }
            }
        }
}

// ---- pairE: epilogue, 1 wave = 1 pair; 256-thr blocks (R18-proven) ----
__global__ __launch_bounds__(256) void pairE_kernel(const unsigned* __restrict__ C,
                                                    const unsigned short* __restrict__ Gswp,
                                                    const float* __restrict__ w1g,
                                                    float* __restrict__ scores) {
    __shared__ __align__(16) char smem[22528];
    const int ib = blockIdx.x;   // caption quad
    const int j = blockIdx.y;    // image
    const int tid = threadIdx.x;
    const int l = tid & 63, wv = tid >> 6;
    const int grp = l >> 4, lw = l & 15;
    const int i = ib * 4 + wv;
    const int p = j * NI + i;
    const int L = j & 3;
    char* const Gd = smem;
    char* const myE = smem + 6144 + wv * 4096;

    for (int u = tid; u < 384; u += 256)
        *(int4*)(Gd + u * 16) = *(const int4*)((const char*)Gswp + (size_t)j * 6144 + u * 16);

    uint2 cv[3][2];
#pragma unroll
    for (int mm3 = 0; mm3 < 3; ++mm3) {
        const int rbase = (2 * L + mm3) * 16 + grp * 4;
        const bool pred = ((rbase * 1821) >> 16) == L;
#pragma unroll
        for (int nn = 0; nn < 2; ++nn)
            cv[mm3][nn] = pred
                ? *(const uint2*)(C + ((size_t)(p * 3 + mm3) * 2 + nn) * 128 + l * 2)
                : make_uint2(0u, 0u);
    }

#pragma unroll
    for (int u = 0; u < 7; ++u) {
        int e = l + u * 64;
        int w = e / 14, pr = e - w * 14 + 18;
        *(unsigned*)(myE + w * 128 + (((pr >> 2) ^ (w & 7)) << 4) + (pr & 3) * 4) = 0u;
    }

#define AV(mm3, nn, reg) ((reg) == 0 ? bf2f(cv[mm3][nn].x) : (reg) == 1 ? bf2f(cv[mm3][nn].x >> 16) \
                          : (reg) == 2 ? bf2f(cv[mm3][nn].y) : bf2f(cv[mm3][nn].y >> 16))

    float inv[3][4];
#pragma unroll
    for (int mm3 = 0; mm3 < 3; ++mm3)
#pragma unroll
        for (int reg = 0; reg < 4; ++reg) {
            float a0 = AV(mm3, 0, reg), a1 = AV(mm3, 1, reg);
            float l0 = a0 > 0.f ? a0 : 0.1f * a0;
            float l1 = a1 > 0.f ? a1 : 0.1f * a1;
            float ss = l0 * l0 + l1 * l1;
            ss += __shfl_xor(ss, 1); ss += __shfl_xor(ss, 2);
            ss += __shfl_xor(ss, 4); ss += __shfl_xor(ss, 8);
            inv[mm3][reg] = 1.f / (sqrtf(ss) + EPSF);
        }

    float mx[2] = {-1e30f, -1e30f};
#pragma unroll
    for (int mm3 = 0; mm3 < 3; ++mm3) {
        int rbase = (2 * L + mm3) * 16 + grp * 4;
        bool pred = ((rbase * 1821) >> 16) == L;
#pragma unroll
        for (int nn = 0; nn < 2; ++nn) {
            float t4 = -1e30f;
#pragma unroll
            for (int reg = 0; reg < 4; ++reg) {
                float a = AV(mm3, nn, reg);
                float lk = a > 0.f ? a : 0.1f * a;
                t4 = fmaxf(t4, LAM_SM * lk * inv[mm3][reg]);
            }
            mx[nn] = pred ? fmaxf(mx[nn], t4) : mx[nn];
        }
    }
#pragma unroll
    for (int nn = 0; nn < 2; ++nn) {
        mx[nn] = fmaxf(mx[nn], __shfl_xor(mx[nn], 16));
        mx[nn] = fmaxf(mx[nn], __shfl_xor(mx[nn], 32));
    }

    float dn[2] = {0.f, 0.f}, nm[2] = {0.f, 0.f};
#pragma unroll
    for (int mm3 = 0; mm3 < 3; ++mm3) {
        int rbase = (2 * L + mm3) * 16 + grp * 4;
        bool pred = ((rbase * 1821) >> 16) == L;
        int rl0 = rbase - 36 * L;
#pragma unroll
        for (int nn = 0; nn < 2; ++nn) {
            int w = nn * 16 + lw;
            float e[4];
#pragma unroll
            for (int reg = 0; reg < 4; ++reg) {
                float a = AV(mm3, nn, reg);
                float lk = a > 0.f ? a : 0.1f * a;
                float tl = LAM_SM * lk * inv[mm3][reg];
                e[reg] = pred ? __expf(tl - mx[nn]) : 0.f;
                dn[nn] += e[reg];
                nm[nn] += e[reg] * a;
            }
            if (pred) {
                char* base = myE + w * 128 + (((rl0 >> 3) ^ (w & 7)) << 4) + (rl0 & 7) * 2;
                *(unsigned*)(base) = pack2bf(e[0], e[1]);
                *(unsigned*)(base + 4) = pack2bf(e[2], e[3]);
            }
        }
    }
#pragma unroll
    for (int nn = 0; nn < 2; ++nn) {
        dn[nn] += __shfl_xor(dn[nn], 16); dn[nn] += __shfl_xor(dn[nn], 32);
        nm[nn] += __shfl_xor(nm[nn], 16); nm[nn] += __shfl_xor(nm[nn], 32);
    }
    __syncthreads();

    f32x4 u[3][2];
#pragma unroll
    for (int m = 0; m < 3; ++m)
#pragma unroll
        for (int nn = 0; nn < 2; ++nn) u[m][nn] = (f32x4){0.f, 0.f, 0.f, 0.f};
#pragma unroll
    for (int ks = 0; ks < 2; ++ks) {
        int sz2 = (((ks * 4 + grp) ^ (lw & 7)) << 4);
        s16x8 ga[3], eb[2];
#pragma unroll
        for (int m = 0; m < 3; ++m)
            ga[m] = *(const s16x8*)(Gd + (m * 16 + lw) * 128 + sz2);
#pragma unroll
        for (int nn = 0; nn < 2; ++nn) {
            int w = nn * 16 + lw;
            eb[nn] = *(const s16x8*)(myE + w * 128 + (((ks * 4 + grp) ^ (w & 7)) << 4));
        }
#pragma unroll
        for (int m = 0; m < 3; ++m)
#pragma unroll
            for (int nn = 0; nn < 2; ++nn)
                u[m][nn] = __builtin_amdgcn_mfma_f32_16x16x32_bf16(ga[m], eb[nn], u[m][nn], 0, 0, 0);
    }
    float qq[2] = {0.f, 0.f};
#pragma unroll
    for (int m = 0; m < 3; ++m)
#pragma unroll
        for (int nn = 0; nn < 2; ++nn) {
            int w = nn * 16 + lw;
            const char* base = myE + w * 128;
#pragma unroll
            for (int rg = 0; rg < 4; rg += 2) {
                int rp = m * 16 + grp * 4 + rg;
                unsigned pv = *(const unsigned*)(base + (((rp >> 3) ^ (w & 7)) << 4) + (rp & 7) * 2);
                qq[nn] += u[m][nn][rg] * bf2f(pv) + u[m][nn][rg + 1] * bf2f(pv >> 16);
            }
        }
#pragma unroll
    for (int nn = 0; nn < 2; ++nn) {
        qq[nn] += __shfl_xor(qq[nn], 16); qq[nn] += __shfl_xor(qq[nn], 32);
    }
    float w1a = w1g[i * 32 + lw], w1b = w1g[i * 32 + 16 + lw];
    float s0 = nm[0] / fmaxf(w1a * sqrtf(fmaxf(qq[0], 0.f)), EPSF * dn[0]);
    float s1 = nm[1] / fmaxf(w1b * sqrtf(fmaxf(qq[1], 0.f)), EPSF * dn[1]);
    float m2 = fmaxf(s0, s1);
    m2 = fmaxf(m2, __shfl_xor(m2, 1)); m2 = fmaxf(m2, __shfl_xor(m2, 2));
    m2 = fmaxf(m2, __shfl_xor(m2, 4)); m2 = fmaxf(m2, __shfl_xor(m2, 8));
    float ssum = __expf(LAM_LSE * (s0 - m2)) + __expf(LAM_LSE * (s1 - m2));
    ssum += __shfl_xor(ssum, 1); ssum += __shfl_xor(ssum, 2);
    ssum += __shfl_xor(ssum, 4); ssum += __shfl_xor(ssum, 8);
    if (l == 0) scores[p] = m2 + logf(ssum) / LAM_LSE;
#undef AV
}

// ---- final hinge loss: 1024 threads, 4-way split per row/col (R15-proven) ----
__global__ __launch_bounds__(1024) void loss_kernel(const float* __restrict__ scores,
                                                    float* __restrict__ out) {
    __shared__ float diag[NJ];
    __shared__ float part[1024];
    __shared__ float red[256];
    const int tid = threadIdx.x;
    if (tid < NJ) diag[tid] = scores[tid * NI + tid];
    __syncthreads();
    const int unit = tid >> 2, q = tid & 3;
    float m = 0.f;
    if (unit < 128) {
        const int a = unit;
        const float da = diag[a];
        for (int k = 0; k < 32; ++k) {
            int b = q * 32 + k;
            float c = MARGIN + scores[a * NI + b] - da;
            if (b != a) m = fmaxf(m, c);
        }
    } else {
        const int b = unit - 128;
        const float db = diag[b];
        for (int k = 0; k < 32; ++k) {
            int a = q * 32 + k;
            float c = MARGIN + scores[a * NI + b] - db;
            if (a != b) m = fmaxf(m, c);
        }
    }
    part[tid] = m;
    __syncthreads();
    if (q == 0)
        red[unit] = fmaxf(fmaxf(part[tid], part[tid + 1]), fmaxf(part[tid + 2], part[tid + 3]));
    __syncthreads();
    for (int st = 128; st > 0; st >>= 1) {
        if (tid < st) red[tid] += red[tid + st];
        __syncthreads();
    }
    if (tid == 0) out[0] = red[0];
}

extern "C" void kernel_launch(void* const* d_in, const int* in_sizes, int n_in,
                              void* d_out, int out_size, void* d_ws, size_t ws_size,
                              hipStream_t stream) {
    const float* im = (const float*)d_in[0];
    const float* s = (const float*)d_in[1];

    unsigned short* imsw = (unsigned short*)d_ws;
    unsigned short* ssw = imsw + IM_ELEMS;
    unsigned short* Gswp = ssw + S_ELEMS;
    float* w1 = (float*)(Gswp + GSW_ELEMS);
    float* scores = w1 + S_ROWS;
    unsigned* C = (unsigned*)(scores + NJ * NI);

    hipFuncSetAttribute((const void*)pairG_kernel,
                        hipFuncAttributeMaxDynamicSharedMemorySize, G_SMEM);
    hipFuncSetAttribute((const void*)prep_kernel,
                        hipFuncAttributeMaxDynamicSharedMemorySize, GRAM_SMEM);

    prep_kernel<<<dim3(NJ + S_ROWS * 128 / 512), dim3(512), GRAM_SMEM, stream>>>(
        im, s, imsw, ssw, w1, Gswp);
    pairG_kernel<<<dim3(NI / 8, NJ / 8), dim3(512), G_SMEM, stream>>>(imsw, ssw, C);
    pairE_kernel<<<dim3(NI / 4, NJ), dim3(256), 0, stream>>>(C, Gswp, w1, scores);
    loss_kernel<<<dim3(1), dim3(1024), 0, stream>>>(scores, (float*)d_out);
}